// Round 4
// baseline (697.302 us; speedup 1.0000x reference)
//
#include <hip/hip_runtime.h>
#include <stdint.h>

typedef unsigned short u16;
typedef unsigned int   u32;

#define SQL  2048
#define SKVL 2048
#define DHD  256
#define SCALE 0.022097086912079612f   // 1/sqrt(2048)

typedef __bf16 bf16x8 __attribute__((ext_vector_type(8)));
typedef float  f32x16 __attribute__((ext_vector_type(16)));

__device__ __forceinline__ u16 f2b(float f) {           // fp32 -> bf16 RNE
    union { float f; u32 i; } v; v.f = f;
    u32 x = v.i;
    return (u16)((x + 0x7fffu + ((x >> 16) & 1u)) >> 16);
}
__device__ __forceinline__ u32 pk2(float a, float b) {  // two bf16 in a u32
    return (u32)f2b(a) | ((u32)f2b(b) << 16);
}

// ---------------------------------------------------------------------------
// Fused no-workspace flash kernel: BQ=64, BKV=64, 32x32x16 MFMA.
// K/V staged in-kernel from fp32 y (L3-resident) with bf16 convert:
//   thread (sp=tid&31, dg=tid>>5) owns kv rows {2sp,2sp+1} x d [32dg,+32).
// LDS layouts (all conflict-free at bank floor):
//   Ks[kv][256d]: 16B chunk c at slot c ^ ror5(kv&31), ror5(k)=(k>>1)|((k&1)<<4)
//   Vt: u32 kv-pairs, row R=d>>1 (256B), chunk c=(d&1)*8+(pair>>2),
//       slot = c ^ (R&15) ^ (((R>>5)&3)<<2), pos = pair&3
// 3 __syncthreads/iter (R0-proven skeleton), mask double-prefetch.
// grid 512 x 256, LDS 74,752 B -> 2 blocks/CU.
// ---------------------------------------------------------------------------
__global__ __launch_bounds__(256, 2)
void fa_nows(const float* __restrict__ x, const float* __restrict__ y,
             const float* __restrict__ mask, float* __restrict__ out)
{
    __shared__ __align__(16) u16 Ks[16384];      // 64 kv x 256 d bf16, swizzled
    __shared__ __align__(16) u32 Vt[8192];       // 128 rows x 64 u32, swizzled
    __shared__ __align__(16) u16 Ps[64 * 72];    // P tile (q, kv), +8 pad
    __shared__ float Lred[2][64];                // row-sum partials per kh

    const int tid  = threadIdx.x;
    const int wv   = tid >> 6;
    const int lane = tid & 63;
    const int n    = lane & 31;
    const int hi   = lane >> 5;
    const int qh   = wv & 1;                     // q half
    const int kh   = wv >> 1;                    // kv half

    const int b  = blockIdx.x >> 5;
    const int q0 = (blockIdx.x & 31) * 64;

    // staging mapping
    const int sp = tid & 31;                     // kv pair index
    const int dg = tid >> 5;                     // d group (32 floats)

    // ---- Q A-frags: A[m=lane&31][k=16s+8hi+j], fp32 -> bf16 ----
    bf16x8 qfrag[16];
    {
        const float* xq = x + ((size_t)(b * SQL + q0 + 32 * qh + n)) * DHD + 8 * hi;
        #pragma unroll
        for (int s = 0; s < 16; ++s) {
            const float4 a  = *(const float4*)(xq + s * 16);
            const float4 c4 = *(const float4*)(xq + s * 16 + 4);
            union { u32 ww[4]; bf16x8 v; } u;
            u.ww[0] = pk2(a.x, a.y);   u.ww[1] = pk2(a.z, a.w);
            u.ww[2] = pk2(c4.x, c4.y); u.ww[3] = pk2(c4.z, c4.w);
            qfrag[s] = u.v;
        }
    }

    f32x16 o0 = {}, o1 = {}, o2 = {}, o3 = {};
    float lsum[16];
    #pragma unroll
    for (int r = 0; r < 16; ++r) lsum[r] = 0.f;

    // mask base: lane covers (q-row per reg r, kv = it*64 + 32kh + n)
    const float* mrow = mask + ((size_t)(b * SQL + q0 + 32 * qh + 4 * hi)) * SKVL
                             + 32 * kh + n;
    #define ROFF(r) ((size_t)(((r) & 3) + 8 * ((r) >> 2)) * SKVL)

    float mkc[16], mkn[16];
    #pragma unroll
    for (int r = 0; r < 16; ++r) mkc[r] = mrow[ROFF(r)];

    // ---- y staging: load tile 0 into packed regs w[32] ----
    // w[k]      = pk(y[2sp  ][dg*32+2k], y[2sp  ][dg*32+2k+1])
    // w[16+k]   = pk(y[2sp+1][dg*32+2k], y[2sp+1][dg*32+2k+1])
    const float* ysrc = y + ((size_t)(b * SKVL + 2 * sp)) * DHD + dg * 32;
    u32 w[32];
    #define LOADCONV(IT) do {                                              \
        const float* s0_ = ysrc + (size_t)(IT) * (64 * DHD);               \
        const float* s1_ = s0_ + DHD;                                      \
        _Pragma("unroll")                                                  \
        for (int j_ = 0; j_ < 4; ++j_) {                                   \
            float4 a_ = *(const float4*)(s0_ + j_ * 8);                    \
            float4 c_ = *(const float4*)(s0_ + j_ * 8 + 4);                \
            w[j_*4+0] = pk2(a_.x, a_.y); w[j_*4+1] = pk2(a_.z, a_.w);      \
            w[j_*4+2] = pk2(c_.x, c_.y); w[j_*4+3] = pk2(c_.z, c_.w);      \
        }                                                                  \
        _Pragma("unroll")                                                  \
        for (int j_ = 0; j_ < 4; ++j_) {                                   \
            float4 a_ = *(const float4*)(s1_ + j_ * 8);                    \
            float4 c_ = *(const float4*)(s1_ + j_ * 8 + 4);                \
            w[16+j_*4+0] = pk2(a_.x, a_.y); w[16+j_*4+1] = pk2(a_.z, a_.w);\
            w[16+j_*4+2] = pk2(c_.x, c_.y); w[16+j_*4+3] = pk2(c_.z, c_.w);\
        }                                                                  \
    } while (0)

    LOADCONV(0);

    for (int it = 0; it < 32; ++it) {
        // ---- stage K/V tile it from packed regs ----
        #pragma unroll
        for (int rs = 0; rs < 2; ++rs) {
            const int kv = 2 * sp + rs;
            const int sl = ((kv >> 1) & 15) | ((kv & 1) << 4);   // ror5(kv&31)
            #pragma unroll
            for (int j = 0; j < 4; ++j) {
                uint4 v4;
                v4.x = w[rs*16 + 4*j + 0]; v4.y = w[rs*16 + 4*j + 1];
                v4.z = w[rs*16 + 4*j + 2]; v4.w = w[rs*16 + 4*j + 3];
                const int slot = (dg * 4 + j) ^ sl;
                *(uint4*)(&Ks[kv * 256 + slot * 8]) = v4;
            }
        }
        #pragma unroll
        for (int i = 0; i < 32; ++i) {          // d = dg*32 + i
            const int sh = 16 * (i & 1);
            const u32 lo  = (w[i >> 1]        >> sh) & 0xFFFFu;
            const u32 hi2 = (w[16 + (i >> 1)] >> sh) & 0xFFFFu;
            const int row  = dg * 16 + (i >> 1);
            const int c    = (i & 1) * 8 + (sp >> 2);
            const int slot = c ^ (row & 15) ^ (((row >> 5) & 3) << 2);
            Vt[row * 64 + slot * 4 + (sp & 3)] = lo | (hi2 << 16);
        }

        __syncthreads();   // B1: Ks/Vt visible

        // ---- S = Q K^T : one 32x32 subtile per wave, K=256 in 16 MFMA ----
        f32x16 sacc = {};
        const int kvloc = 32 * kh + n;
        const int slk = ((kvloc >> 1) & 15) | ((kvloc & 1) << 4);
        #pragma unroll
        for (int s = 0; s < 16; ++s) {
            const int slot = (2 * s + hi) ^ slk;
            bf16x8 bf = *(const bf16x8*)(&Ks[kvloc * 256 + slot * 8]);
            sacc = __builtin_amdgcn_mfma_f32_32x32x16_bf16(qfrag[s], bf, sacc, 0, 0, 0);
        }

        // ---- p = exp(s*mask*scale), accumulate row sums, write Ps ----
        #pragma unroll
        for (int r = 0; r < 16; ++r) {
            const int rowloc = (r & 3) + 8 * (r >> 2) + 4 * hi;
            float pv = __expf(sacc[r] * mkc[r] * SCALE);
            lsum[r] += pv;
            Ps[(32 * qh + rowloc) * 72 + 32 * kh + n] = f2b(pv);
        }

        // ---- load y tile it+1 into w (cover = barrier + PV + barrier) ----
        if (it + 1 < 32) LOADCONV(it + 1);
        // ---- mask prefetch it+1 ----
        if (it + 1 < 32) {
            const size_t kvn = (size_t)(it + 1) * 64;
            #pragma unroll
            for (int r = 0; r < 16; ++r) mkn[r] = mrow[ROFF(r) + kvn];
        }

        __syncthreads();   // B2: Ps ready

        // ---- O += P V : wave covers q[32qh,+32) x d[128kh,+128) ----
        bf16x8 pa[4];
        #pragma unroll
        for (int s = 0; s < 4; ++s)
            pa[s] = *(const bf16x8*)(&Ps[(32 * qh + n) * 72 + 16 * s + 8 * hi]);
        #pragma unroll
        for (int t = 0; t < 4; ++t) {
            const int d   = 128 * kh + 32 * t + n;
            const int row = d >> 1;
            const int cb  = (d & 1) * 8;
            const int rx  = (row & 15) ^ (((row >> 5) & 3) << 2);
            f32x16 acc = (t == 0) ? o0 : (t == 1) ? o1 : (t == 2) ? o2 : o3;
            #pragma unroll
            for (int s = 0; s < 4; ++s) {
                const int slot = (cb + 2 * s + hi) ^ rx;
                bf16x8 bf = *(const bf16x8*)((const u16*)&Vt[row * 64 + slot * 4]);
                acc = __builtin_amdgcn_mfma_f32_32x32x16_bf16(pa[s], bf, acc, 0, 0, 0);
            }
            if (t == 0) o0 = acc; else if (t == 1) o1 = acc; else if (t == 2) o2 = acc; else o3 = acc;
        }

        __syncthreads();   // B3: Vt/Ks/Ps reads done -> next stage may overwrite

        #pragma unroll
        for (int r = 0; r < 16; ++r) mkc[r] = mkn[r];
    }

    // ---- row-sum reduction: over 32 lanes sharing each row, then across kh ----
    #pragma unroll
    for (int r = 0; r < 16; ++r) {
        float v = lsum[r];
        v += __shfl_xor(v, 1);
        v += __shfl_xor(v, 2);
        v += __shfl_xor(v, 4);
        v += __shfl_xor(v, 8);
        v += __shfl_xor(v, 16);
        if (n == 0) {
            const int rowloc = (r & 3) + 8 * (r >> 2) + 4 * hi;
            Lred[kh][32 * qh + rowloc] = v;
        }
    }
    __syncthreads();

    float inv[16];
    #pragma unroll
    for (int r = 0; r < 16; ++r) {
        const int qloc = 32 * qh + (r & 3) + 8 * (r >> 2) + 4 * hi;
        inv[r] = 1.0f / (Lred[0][qloc] + Lred[1][qloc]);
    }

    // ---- epilogue: out = O/l + x ----
    #pragma unroll
    for (int r = 0; r < 16; ++r) {
        const int qloc = 32 * qh + (r & 3) + 8 * (r >> 2) + 4 * hi;
        const size_t rowoff = ((size_t)(b * SQL + q0 + qloc)) * DHD;
        #pragma unroll
        for (int t = 0; t < 4; ++t) {
            const int d = 128 * kh + 32 * t + n;
            const float ov = (t == 0) ? o0[r] : (t == 1) ? o1[r] : (t == 2) ? o2[r] : o3[r];
            out[rowoff + d] = ov * inv[r] + x[rowoff + d];
        }
    }
}

extern "C" void kernel_launch(void* const* d_in, const int* in_sizes, int n_in,
                              void* d_out, int out_size, void* d_ws, size_t ws_size,
                              hipStream_t stream) {
    const float* x    = (const float*)d_in[0];
    const float* y    = (const float*)d_in[1];
    const float* mask = (const float*)d_in[2];
    float* out        = (float*)d_out;
    (void)d_ws; (void)ws_size;   // workspace deliberately untouched (poison test)

    fa_nows<<<512, 256, 0, stream>>>(x, y, mask, out);
}

// Round 5
// 487.405 us; speedup vs baseline: 1.4306x; 1.4306x over previous
//
#include <hip/hip_runtime.h>
#include <stdint.h>

typedef unsigned short u16;
typedef unsigned int   u32;

#define SQL  2048
#define SKVL 2048
#define DHD  256
#define SCALE 0.022097086912079612f   // 1/sqrt(2048)

typedef __bf16 bf16x8 __attribute__((ext_vector_type(8)));
typedef float  f32x16 __attribute__((ext_vector_type(16)));

__device__ __forceinline__ u16 f2b(float f) {           // fp32 -> bf16 RNE
    union { float f; u32 i; } v; v.f = f;
    u32 x = v.i;
    return (u16)((x + 0x7fffu + ((x >> 16) & 1u)) >> 16);
}
__device__ __forceinline__ u32 pk2(float a, float b) {  // two bf16 in a u32
    return (u32)f2b(a) | ((u32)f2b(b) << 16);
}

__device__ __forceinline__ void async_cp16(const void* g, void* l) {
    __builtin_amdgcn_global_load_lds(
        (const __attribute__((address_space(1))) u32*)g,
        (__attribute__((address_space(3))) u32*)l, 16, 0, 0);
}

// ---------------------------------------------------------------------------
// Prepass:
//  yb : bf16 kv-major, 512B rows, 16B chunk c at slot c ^ (kv & 31)
//       (R3-validated: QK b128 reads conflict-free)
//  ybT: V in kv-pair u32 layout per 64-kv tile (R4-validated read pattern):
//       u32[(b*32+kvblk)*8192 + row*64 + slot*4 + pos]
//         row = d>>1 (256B rows), c = (d&1)*8 + g, slot = c ^ (row&15) ^
//         (((row>>5)&3)<<2), pos = q;  value = pk(V[kv0+8g+2q][d],
//         V[kv0+8g+2q+1][d])
//       -> DMA copies tile linearly into LDS Vt (no manual staging writes).
// grid 1024 x 256
// ---------------------------------------------------------------------------
__global__ __launch_bounds__(256)
void prepass(const float* __restrict__ y, u16* __restrict__ ws)
{
    u16* yb   = ws;                        // 8,388,608 u16 (16 MiB)
    u32* ybT  = (u32*)(ws + 8388608);      // 4,194,304 u32 (16 MiB)

    const int tid = threadIdx.x;
    if (blockIdx.x < 512) {
        // ---- yb: kv-major swizzled (slot = chunk ^ (kv&31)) ----
        const int b   = blockIdx.x >> 5;
        const int seg = blockIdx.x & 31;          // 64 kv rows
        const int r   = tid >> 2;                 // 0..63 local kv
        const int dq  = tid & 3;                  // 64-d quarter
        const int kvg = seg * 64 + r;
        const float* src = y + ((size_t)(b * SKVL + kvg)) * DHD + dq * 64;
        u16* dst = yb + ((size_t)(b * SKVL + kvg)) * DHD;
        #pragma unroll
        for (int j = 0; j < 8; ++j) {             // 8 chunks of 8 floats
            const float4 a = *(const float4*)(src + j * 8);
            const float4 c4 = *(const float4*)(src + j * 8 + 4);
            union { u32 w[4]; uint4 q; } u;
            u.w[0] = pk2(a.x, a.y);   u.w[1] = pk2(a.z, a.w);
            u.w[2] = pk2(c4.x, c4.y); u.w[3] = pk2(c4.z, c4.w);
            const int pos = (dq * 8 + j) ^ (kvg & 31);
            *(uint4*)(dst + pos * 8) = u.q;
        }
    } else {
        // ---- ybT: kv-pair V layout ----
        const int j     = blockIdx.x - 512;
        const int b     = j >> 5;
        const int kvblk = j & 31;                 // kv [kvblk*64, +64)
        const int d     = tid;                    // 0..255
        const int kv0   = kvblk * 64;
        const int row   = d >> 1;
        const int rx    = (row & 15) ^ (((row >> 5) & 3) << 2);
        u32* dst = ybT + ((size_t)(b * 32 + kvblk)) * 8192 + row * 64;
        #pragma unroll
        for (int g = 0; g < 8; ++g) {             // kv 8g..8g+7
            float v[8];
            #pragma unroll
            for (int e = 0; e < 8; ++e)
                v[e] = y[((size_t)(b * SKVL + kv0 + 8 * g + e)) * DHD + d];
            union { u32 w[4]; uint4 q; } u;
            #pragma unroll
            for (int q2 = 0; q2 < 4; ++q2)
                u.w[q2] = pk2(v[2 * q2], v[2 * q2 + 1]);
            const int slot = (((d & 1) * 8) + g) ^ rx;
            *(uint4*)(dst + slot * 4) = u.q;
        }
    }
}

// ---------------------------------------------------------------------------
// Main flash kernel: BQ=64, BKV=64, 32x32x16 MFMA, DMA-staged swizzled tiles.
// R0-proven 3-__syncthreads skeleton; conflict-free LDS layouts (R3/R4-
// validated read patterns); setprio around MFMA clusters.
// grid 512 x 256, 2 blocks/CU (LDS 75,008 B)
// ---------------------------------------------------------------------------
__global__ __launch_bounds__(256, 2)
void fa_main(const float* __restrict__ x, const float* __restrict__ mask,
             const u16* __restrict__ ws, float* __restrict__ out)
{
    __shared__ __align__(16) u16 Ks[16384];      // 64 kv x 256 d bf16, &31-swz
    __shared__ __align__(16) u32 Vt[8192];       // 128 rows x 64 u32, kv-pair swz
    __shared__ __align__(16) u16 Ps[64 * 72];    // P tile (q, kv), +8 pad
    __shared__ float Lred[2][64];                // row-sum partials per kh

    const u16* yb  = ws;
    const u32* ybT = (const u32*)(ws + 8388608);

    const int tid  = threadIdx.x;
    const int wv   = tid >> 6;
    const int lane = tid & 63;
    const int n    = lane & 31;
    const int hi   = lane >> 5;
    const int qh   = wv & 1;                     // q half
    const int kh   = wv >> 1;                    // kv half

    const int b  = blockIdx.x >> 5;
    const int q0 = (blockIdx.x & 31) * 64;

    // ---- Q A-frags: A[m=lane&31][k=16s+8hi+j], fp32 -> bf16 ----
    bf16x8 qfrag[16];
    {
        const float* xq = x + ((size_t)(b * SQL + q0 + 32 * qh + n)) * DHD + 8 * hi;
        #pragma unroll
        for (int s = 0; s < 16; ++s) {
            const float4 a  = *(const float4*)(xq + s * 16);
            const float4 c4 = *(const float4*)(xq + s * 16 + 4);
            union { u32 w[4]; bf16x8 v; } u;
            u.w[0] = pk2(a.x, a.y);   u.w[1] = pk2(a.z, a.w);
            u.w[2] = pk2(c4.x, c4.y); u.w[3] = pk2(c4.z, c4.w);
            qfrag[s] = u.v;
        }
    }

    f32x16 o0 = {}, o1 = {}, o2 = {}, o3 = {};
    float lsum[16];
    #pragma unroll
    for (int r = 0; r < 16; ++r) lsum[r] = 0.f;

    // mask base: lane covers (q-row per reg r, kv = it*64 + 32kh + n)
    const float* mrow = mask + ((size_t)(b * SQL + q0 + 32 * qh + 4 * hi)) * SKVL
                             + 32 * kh + n;
    #define ROFF(r) ((size_t)(((r) & 3) + 8 * ((r) >> 2)) * SKVL)

    float mkc[16], mkn[16];
    #pragma unroll
    for (int r = 0; r < 16; ++r) mkc[r] = mrow[ROFF(r)];

    // ---- DMA tile 0 ----
    {
        const char* gk = (const char*)(yb + ((size_t)b * SKVL) * DHD) + wv * 8192 + lane * 16;
        const char* gv = (const char*)(ybT + ((size_t)(b * 32)) * 8192) + wv * 8192 + lane * 16;
        char* lk = ((char*)Ks) + wv * 8192;
        char* lv = ((char*)Vt) + wv * 8192;
        #pragma unroll
        for (int i = 0; i < 8; ++i) { async_cp16(gk + i * 1024, lk + i * 1024);
                                      async_cp16(gv + i * 1024, lv + i * 1024); }
    }
    __syncthreads();   // drain tile-0 DMA

    for (int it = 0; it < 32; ++it) {
        // prefetch next mask tile (in flight across the whole iteration)
        const size_t kvn = (it + 1 < 32) ? (size_t)(it + 1) * 64 : 0;
        #pragma unroll
        for (int r = 0; r < 16; ++r) mkn[r] = mrow[ROFF(r) + kvn];

        // ---- S = Q K^T : one 32x32 subtile per wave, K=256 in 16 MFMA ----
        f32x16 sacc = {};
        const int kvloc = 32 * kh + n;
        __builtin_amdgcn_s_setprio(1);
        #pragma unroll
        for (int s = 0; s < 16; ++s) {
            const int p = (2 * s + hi) ^ (kvloc & 31);
            bf16x8 bf = *(const bf16x8*)(&Ks[kvloc * 256 + p * 8]);
            sacc = __builtin_amdgcn_mfma_f32_32x32x16_bf16(qfrag[s], bf, sacc, 0, 0, 0);
        }
        __builtin_amdgcn_s_setprio(0);

        // ---- p = exp(s*mask*scale), accumulate row sums, write Ps ----
        #pragma unroll
        for (int r = 0; r < 16; ++r) {
            const int rowloc = (r & 3) + 8 * (r >> 2) + 4 * hi;
            float pv = __expf(sacc[r] * mkc[r] * SCALE);
            lsum[r] += pv;
            Ps[(32 * qh + rowloc) * 72 + 32 * kh + n] = f2b(pv);
        }

        __syncthreads();   // C: Ps complete (cross-wave), all QK reads done

        // Ks DMA for next tile — hidden under PV
        if (it + 1 < 32) {
            const char* gk = (const char*)(yb + ((size_t)(b * SKVL + (it + 1) * 64)) * DHD)
                             + wv * 8192 + lane * 16;
            char* lk = ((char*)Ks) + wv * 8192;
            #pragma unroll
            for (int i = 0; i < 8; ++i) async_cp16(gk + i * 1024, lk + i * 1024);
        }

        // ---- O += P V : wave covers q[32qh,+32) x d[128kh,+128) ----
        bf16x8 pa[4];
        #pragma unroll
        for (int s = 0; s < 4; ++s)
            pa[s] = *(const bf16x8*)(&Ps[(32 * qh + n) * 72 + 16 * s + 8 * hi]);
        __builtin_amdgcn_s_setprio(1);
        #pragma unroll
        for (int t = 0; t < 4; ++t) {
            const int d   = 128 * kh + 32 * t + n;
            const int row = d >> 1;
            const int cb  = (d & 1) * 8;
            const int rx  = (row & 15) ^ (((row >> 5) & 3) << 2);
            f32x16 acc = (t == 0) ? o0 : (t == 1) ? o1 : (t == 2) ? o2 : o3;
            #pragma unroll
            for (int s = 0; s < 4; ++s) {
                const int slot = (cb + 2 * s + hi) ^ rx;
                bf16x8 bf = *(const bf16x8*)((const u16*)&Vt[row * 64 + slot * 4]);
                acc = __builtin_amdgcn_mfma_f32_32x32x16_bf16(pa[s], bf, acc, 0, 0, 0);
            }
            if (t == 0) o0 = acc; else if (t == 1) o1 = acc; else if (t == 2) o2 = acc; else o3 = acc;
        }
        __builtin_amdgcn_s_setprio(0);

        __syncthreads();   // A: PV done reading Vt/Ps

        // Vt DMA for next tile
        if (it + 1 < 32) {
            const char* gv = (const char*)(ybT + ((size_t)(b * 32 + it + 1)) * 8192)
                             + wv * 8192 + lane * 16;
            char* lv = ((char*)Vt) + wv * 8192;
            #pragma unroll
            for (int i = 0; i < 8; ++i) async_cp16(gv + i * 1024, lv + i * 1024);
        }
        __syncthreads();   // B: drain DMA before next QK

        #pragma unroll
        for (int r = 0; r < 16; ++r) mkc[r] = mkn[r];
    }

    // ---- row-sum reduction: over 32 lanes sharing each row, then across kh ----
    #pragma unroll
    for (int r = 0; r < 16; ++r) {
        float v = lsum[r];
        v += __shfl_xor(v, 1);
        v += __shfl_xor(v, 2);
        v += __shfl_xor(v, 4);
        v += __shfl_xor(v, 8);
        v += __shfl_xor(v, 16);
        if (n == 0) {
            const int rowloc = (r & 3) + 8 * (r >> 2) + 4 * hi;
            Lred[kh][32 * qh + rowloc] = v;
        }
    }
    __syncthreads();

    float inv[16];
    #pragma unroll
    for (int r = 0; r < 16; ++r) {
        const int qloc = 32 * qh + (r & 3) + 8 * (r >> 2) + 4 * hi;
        inv[r] = 1.0f / (Lred[0][qloc] + Lred[1][qloc]);
    }

    // ---- epilogue: out = O/l + x ----
    #pragma unroll
    for (int r = 0; r < 16; ++r) {
        const int qloc = 32 * qh + (r & 3) + 8 * (r >> 2) + 4 * hi;
        const size_t rowoff = ((size_t)(b * SQL + q0 + qloc)) * DHD;
        #pragma unroll
        for (int t = 0; t < 4; ++t) {
            const int d = 128 * kh + 32 * t + n;
            const float ov = (t == 0) ? o0[r] : (t == 1) ? o1[r] : (t == 2) ? o2[r] : o3[r];
            out[rowoff + d] = ov * inv[r] + x[rowoff + d];
        }
    }
}

// ---------------------------------------------------------------------------
// Fallback (round-3 kernel) if ws_size is too small for the prepass buffers
// ---------------------------------------------------------------------------
#define FKSS 264
#define FVTG 328
#define FPSS 40

__global__ __launch_bounds__(256, 2)
void fa_fallback(const float* __restrict__ x, const float* __restrict__ y,
                 const float* __restrict__ mask, float* __restrict__ out)
{
    __shared__ __align__(16) u16 Ks[32 * FKSS];
    __shared__ __align__(16) u32 Vt[16 * FVTG];
    __shared__ __align__(16) u16 Ps[64 * FPSS];

    const int tid  = threadIdx.x;
    const int wv   = tid >> 6;
    const int lane = tid & 63;
    const int l16  = lane & 15;
    const int quad = lane >> 4;
    const int b  = blockIdx.x >> 5;
    const int q0 = (blockIdx.x & 31) * 64;

    bf16x8 qfrag[8];
    {
        const float* xq = x + ((size_t)(b * SQL + q0 + wv * 16 + l16)) * DHD + quad * 8;
        #pragma unroll
        for (int s = 0; s < 8; ++s) {
            const float4 a = *(const float4*)(xq + s * 32);
            const float4 c = *(const float4*)(xq + s * 32 + 4);
            union { u32 w[4]; bf16x8 v; } u;
            u.w[0] = pk2(a.x, a.y); u.w[1] = pk2(a.z, a.w);
            u.w[2] = pk2(c.x, c.y); u.w[3] = pk2(c.z, c.w);
            qfrag[s] = u.v;
        }
    }
    f32x16 oo[4] = {};
    float ls[4] = {0.f, 0.f, 0.f, 0.f};
    float4 o[16];
    #pragma unroll
    for (int t = 0; t < 16; ++t) o[t] = float4{0.f, 0.f, 0.f, 0.f};
    const int kv2 = tid & 15;
    const int dc  = tid >> 4;
    const float* ybase = y + ((size_t)b * SKVL) * DHD;
    float4 r0[4], r1[4];
    {
        const float* p0 = ybase + (size_t)(2 * kv2) * DHD + dc * 16;
        const float* p1 = p0 + DHD;
        #pragma unroll
        for (int p = 0; p < 4; ++p) { r0[p] = *(const float4*)(p0 + p * 4);
                                      r1[p] = *(const float4*)(p1 + p * 4); }
    }
    const float* mbase = mask + ((size_t)(b * SQL + q0 + wv * 16 + quad * 4)) * SKVL;
    float mkc0[4], mkc1[4], mkn0[4], mkn1[4];
    #pragma unroll
    for (int r = 0; r < 4; ++r) {
        const float* mp = mbase + (size_t)r * SKVL;
        mkc0[r] = mp[l16]; mkc1[r] = mp[16 + l16];
    }
    for (int it = 0; it < 64; ++it) {
        const int kv0 = it * 32;
        __syncthreads();
        {
            u16 e0[16], e1[16];
            #pragma unroll
            for (int p = 0; p < 4; ++p) {
                e0[p*4+0]=f2b(r0[p].x); e0[p*4+1]=f2b(r0[p].y);
                e0[p*4+2]=f2b(r0[p].z); e0[p*4+3]=f2b(r0[p].w);
                e1[p*4+0]=f2b(r1[p].x); e1[p*4+1]=f2b(r1[p].y);
                e1[p*4+2]=f2b(r1[p].z); e1[p*4+3]=f2b(r1[p].w);
            }
            union { u32 w[4]; uint4 q; } k0a, k0b, k1a, k1b;
            #pragma unroll
            for (int i = 0; i < 4; ++i) {
                k0a.w[i] = (u32)e0[2*i]   | ((u32)e0[2*i+1]   << 16);
                k0b.w[i] = (u32)e0[8+2*i] | ((u32)e0[8+2*i+1] << 16);
                k1a.w[i] = (u32)e1[2*i]   | ((u32)e1[2*i+1]   << 16);
                k1b.w[i] = (u32)e1[8+2*i] | ((u32)e1[8+2*i+1] << 16);
            }
            *(uint4*)(&Ks[(2*kv2)  *FKSS + dc*16])     = k0a.q;
            *(uint4*)(&Ks[(2*kv2)  *FKSS + dc*16 + 8]) = k0b.q;
            *(uint4*)(&Ks[(2*kv2+1)*FKSS + dc*16])     = k1a.q;
            *(uint4*)(&Ks[(2*kv2+1)*FKSS + dc*16 + 8]) = k1b.q;
            #pragma unroll
            for (int e = 0; e < 16; ++e)
                Vt[dc*FVTG + e*20 + kv2] = (u32)e0[e] | ((u32)e1[e] << 16);
        }
        __syncthreads();
        if (it + 1 < 64) {
            const float* p0 = ybase + (size_t)(kv0 + 32 + 2 * kv2) * DHD + dc * 16;
            const float* p1 = p0 + DHD;
            #pragma unroll
            for (int p = 0; p < 4; ++p) { r0[p] = *(const float4*)(p0 + p * 4);
                                          r1[p] = *(const float4*)(p1 + p * 4); }
        }
        {
            const int kvn2 = (it + 1 < 64) ? (kv0 + 32) : 0;
            #pragma unroll
            for (int r = 0; r < 4; ++r) {
                const float* mp = mbase + (size_t)r * SKVL + kvn2;
                mkn0[r] = mp[l16]; mkn1[r] = mp[16 + l16];
            }
        }
        typedef float f32x4_t __attribute__((ext_vector_type(4)));
        f32x4_t acc0 = {}, acc1 = {};
        #pragma unroll
        for (int s = 0; s < 8; ++s) {
            bf16x8 b0 = *(const bf16x8*)(&Ks[ l16     * FKSS + s*32 + quad*8]);
            bf16x8 b1 = *(const bf16x8*)(&Ks[(16+l16) * FKSS + s*32 + quad*8]);
            acc0 = __builtin_amdgcn_mfma_f32_16x16x32_bf16(qfrag[s], b0, acc0, 0, 0, 0);
            acc1 = __builtin_amdgcn_mfma_f32_16x16x32_bf16(qfrag[s], b1, acc1, 0, 0, 0);
        }
        #pragma unroll
        for (int r = 0; r < 4; ++r) {
            float p0 = __expf(acc0[r] * mkc0[r] * SCALE);
            float p1 = __expf(acc1[r] * mkc1[r] * SCALE);
            ls[r] += p0 + p1;
            u16* pr = &Ps[(wv*16 + quad*4 + r) * FPSS];
            pr[l16]      = f2b(p0);
            pr[16 + l16] = f2b(p1);
        }
        bf16x8 afrag = *(const bf16x8*)(&Ps[(wv*16 + l16) * FPSS + quad*8]);
        #pragma unroll
        for (int t = 0; t < 16; ++t) {
            bf16x8 bfrag = *(const bf16x8*)(&Vt[t*FVTG + l16*20 + quad*4]);
            f32x4_t a4; a4[0]=o[t].x; a4[1]=o[t].y; a4[2]=o[t].z; a4[3]=o[t].w;
            a4 = __builtin_amdgcn_mfma_f32_16x16x32_bf16(afrag, bfrag, a4, 0, 0, 0);
            o[t].x=a4[0]; o[t].y=a4[1]; o[t].z=a4[2]; o[t].w=a4[3];
        }
        #pragma unroll
        for (int r = 0; r < 4; ++r) { mkc0[r] = mkn0[r]; mkc1[r] = mkn1[r]; }
    }
    #pragma unroll
    for (int r = 0; r < 4; ++r) {
        float v = ls[r];
        v += __shfl_xor(v, 1); v += __shfl_xor(v, 2);
        v += __shfl_xor(v, 4); v += __shfl_xor(v, 8);
        ls[r] = 1.0f / v;
    }
    const int qrow = q0 + wv * 16 + quad * 4;
    #pragma unroll
    for (int r = 0; r < 4; ++r) {
        const size_t rowoff = ((size_t)(b * SQL + qrow + r)) * DHD;
        const float* op = (const float*)&o[0];
        #pragma unroll
        for (int t = 0; t < 16; ++t) {
            const int d = t * 16 + l16;
            out[rowoff + d] = op[t * 4 + r] * ls[r] + x[rowoff + d];
        }
    }
    (void)oo;
}

extern "C" void kernel_launch(void* const* d_in, const int* in_sizes, int n_in,
                              void* d_out, int out_size, void* d_ws, size_t ws_size,
                              hipStream_t stream) {
    const float* x    = (const float*)d_in[0];
    const float* y    = (const float*)d_in[1];
    const float* mask = (const float*)d_in[2];
    float* out        = (float*)d_out;

    if (ws_size >= 33554432ull) {
        prepass<<<1024, 256, 0, stream>>>(y, (u16*)d_ws);
        fa_main<<<512, 256, 0, stream>>>(x, mask, (const u16*)d_ws, out);
    } else {
        fa_fallback<<<512, 256, 0, stream>>>(x, y, mask, out);
    }
}